// Round 1
// baseline (3127.556 us; speedup 1.0000x reference)
//
#include <hip/hip_runtime.h>

// Problem constants: B=4096, K=16, H=32, HM=128, STEPS=8
#define OFF_MS  524288   // local_depths  [B,8,16] = 524288
#define OFF_CS  557056   // march_steps   [B,8,1]  = 32768
#define OFF_IP  1081344  // cossims       [B,8,16] = 524288
#define OFF_CUM 1179648  // implicit_pts  [B,8,3]  = 98304
#define OFF_EPS 1183744  // cum [B,1]=4096, eps [B,1]=4096

struct Params {
  const float *knn, *query, *fw1, *fb1, *fw2, *fb2, *fw3, *fb3, *qkv_w,
    *ptp_w1, *ptp_b1, *ptp_w2, *ptp_b2, *pta_w1, *pta_b1, *pta_w2, *pta_b2,
    *caq_w, *caq_b, *cak_w, *cak_b, *cav_w, *cav_b,
    *cap_w1, *cap_b1, *cap_w2, *cap_b2, *caa_w1, *caa_b1, *caa_w2, *caa_b2,
    *im_w1, *im_b1, *im_w2, *im_b2, *im_w3, *im_b3,
    *ep_w1, *ep_b1, *ep_w2, *ep_b2, *ep_w3, *ep_b3;
  float *o_ld, *o_ms, *o_cs, *o_ip, *o_cum, *o_eps;
};
static_assert(sizeof(Params) == 49 * sizeof(void*), "Params layout");

__launch_bounds__(256, 2)
__global__ void puray_kernel(Params p) {
  const int b = blockIdx.x;
  const int t = threadIdx.x;

  __shared__ float s_wA[4096];            // ptp_w2 | cap_w2   [128][32]
  __shared__ float s_wC[4096];            // pta_w2 | caa_w2   [128][32]
  __shared__ float s_hid[2 * 16 * 132];   // hidden slabs, stride 132 (also phase-A scratch)
  __shared__ float s_rpe[2 * 16 * 32];    // rpe (C) / pe (D) (also phase-A scratch)
  __shared__ float s_sim[2 * 16 * 33];    // simin/sim, stride 33 (also ain in D)
  __shared__ float s_q[512], s_k[512], s_v[512], s_feats[512], s_vv[512];
  __shared__ float s_coords[48];
  __shared__ float s_relv[48];
  __shared__ float s_reld[16];
  __shared__ float s_opc[3], s_op[3], s_imp[3], s_tang[3], s_qry[3];
  __shared__ float s_h1[32], s_h2[32], s_opf[32], s_qq[32], s_ca[35];
  __shared__ float s_cum, s_step;

  // ---- stage phase-C big weights into LDS ----
  {
    const float4* srcA = (const float4*)p.ptp_w2;
    const float4* srcC = (const float4*)p.pta_w2;
    float4* dA = (float4*)s_wA;
    float4* dC = (float4*)s_wC;
#pragma unroll
    for (int m = 0; m < 4; ++m) {
      dA[t + 256 * m] = srcA[t + 256 * m];
      dC[t + 256 * m] = srcC[t + 256 * m];
    }
  }
  if (t < 48) s_coords[t] = p.knn[b * 48 + t];
  if (t >= 64 && t < 67) s_qry[t - 64] = p.query[b * 3 + t - 64];
  if (t == 67) s_cum = 0.f;
  if (t >= 68 && t < 71) s_op[t - 68] = 0.f;
  __syncthreads();

  // ---- Phase A: feats = feat_mlp(knn_coords) : 16 points, 3->32->32->32 ----
#pragma unroll
  for (int m = 0; m < 2; ++m) {
    const int l = t + 256 * m, pp = l >> 5, j = l & 31;
    float a = p.fb1[j];
#pragma unroll
    for (int c = 0; c < 3; ++c) a = fmaf(s_coords[pp * 3 + c], p.fw1[c * 32 + j], a);
    s_hid[l] = fmaxf(a, 0.f);
  }
  __syncthreads();
#pragma unroll
  for (int m = 0; m < 2; ++m) {
    const int l = t + 256 * m, pp = l >> 5, j = l & 31;
    float a = p.fb2[j];
    for (int i = 0; i < 32; ++i) a = fmaf(s_hid[pp * 32 + i], p.fw2[i * 32 + j], a);
    s_rpe[l] = fmaxf(a, 0.f);
  }
  __syncthreads();
#pragma unroll
  for (int m = 0; m < 2; ++m) {
    const int l = t + 256 * m, pp = l >> 5, j = l & 31;
    float a = p.fb3[j];
    for (int i = 0; i < 32; ++i) a = fmaf(s_rpe[pp * 32 + i], p.fw3[i * 32 + j], a);
    s_feats[l] = a;
  }
  __syncthreads();

  // ---- Phase B: qkv = feats @ qkv_w  (no bias) ----
#pragma unroll
  for (int m = 0; m < 6; ++m) {
    const int l = t + 256 * m, pp = l / 96, o = l % 96;
    float a = 0.f;
    for (int i = 0; i < 32; ++i) a = fmaf(s_feats[pp * 32 + i], p.qkv_w[i * 96 + o], a);
    if (o < 32) s_q[pp * 32 + o] = a;
    else if (o < 64) s_k[pp * 32 + o - 32] = a;
    else s_v[pp * 32 + o - 64] = a;
  }
  __syncthreads();

  // ---- Phase C: point transformer, 2 output rows i in flight ----
  for (int ig = 0; ig < 16; ig += 2) {
    const int g = t >> 7, u = t & 127;
    const int i = ig + g;
    {
      // fused rpe (3->128 hidden in regs) + layer2 into rpe, and simin = q[i]-k[j]+rpe
      const int j = u >> 3, h0 = (u & 7) * 4;
      const float r0 = s_coords[i * 3 + 0] - s_coords[j * 3 + 0];
      const float r1 = s_coords[i * 3 + 1] - s_coords[j * 3 + 1];
      const float r2 = s_coords[i * 3 + 2] - s_coords[j * 3 + 2];
      float a0 = p.ptp_b2[h0 + 0], a1 = p.ptp_b2[h0 + 1], a2 = p.ptp_b2[h0 + 2], a3 = p.ptp_b2[h0 + 3];
      for (int d = 0; d < 128; ++d) {
        const float hv = fmaxf(fmaf(r0, p.ptp_w1[d],
                         fmaf(r1, p.ptp_w1[128 + d],
                         fmaf(r2, p.ptp_w1[256 + d], p.ptp_b1[d]))), 0.f);
        const float4 w2 = *(const float4*)&s_wA[d * 32 + h0];
        a0 = fmaf(hv, w2.x, a0); a1 = fmaf(hv, w2.y, a1);
        a2 = fmaf(hv, w2.z, a2); a3 = fmaf(hv, w2.w, a3);
      }
      const int base = g * 16 + j;
      s_rpe[base * 32 + h0 + 0] = a0; s_rpe[base * 32 + h0 + 1] = a1;
      s_rpe[base * 32 + h0 + 2] = a2; s_rpe[base * 32 + h0 + 3] = a3;
      s_sim[base * 33 + h0 + 0] = s_q[i * 32 + h0 + 0] - s_k[j * 32 + h0 + 0] + a0;
      s_sim[base * 33 + h0 + 1] = s_q[i * 32 + h0 + 1] - s_k[j * 32 + h0 + 1] + a1;
      s_sim[base * 33 + h0 + 2] = s_q[i * 32 + h0 + 2] - s_k[j * 32 + h0 + 2] + a2;
      s_sim[base * 33 + h0 + 3] = s_q[i * 32 + h0 + 3] - s_k[j * 32 + h0 + 3] + a3;
    }
    __syncthreads();
    {
      // hidden2 = relu(simin @ pta_w1 + b1) -> s_hid
      const int j = u >> 3, d0 = (u & 7) * 16;
      float acc[16];
#pragma unroll
      for (int x = 0; x < 16; ++x) acc[x] = p.pta_b1[d0 + x];
      for (int h = 0; h < 32; ++h) {
        const float a = s_sim[(g * 16 + j) * 33 + h];
        const float4 w0 = *(const float4*)&p.pta_w1[h * 128 + d0];
        const float4 w1v = *(const float4*)&p.pta_w1[h * 128 + d0 + 4];
        const float4 w2v = *(const float4*)&p.pta_w1[h * 128 + d0 + 8];
        const float4 w3v = *(const float4*)&p.pta_w1[h * 128 + d0 + 12];
        acc[0] = fmaf(a, w0.x, acc[0]);   acc[1] = fmaf(a, w0.y, acc[1]);
        acc[2] = fmaf(a, w0.z, acc[2]);   acc[3] = fmaf(a, w0.w, acc[3]);
        acc[4] = fmaf(a, w1v.x, acc[4]);  acc[5] = fmaf(a, w1v.y, acc[5]);
        acc[6] = fmaf(a, w1v.z, acc[6]);  acc[7] = fmaf(a, w1v.w, acc[7]);
        acc[8] = fmaf(a, w2v.x, acc[8]);  acc[9] = fmaf(a, w2v.y, acc[9]);
        acc[10] = fmaf(a, w2v.z, acc[10]); acc[11] = fmaf(a, w2v.w, acc[11]);
        acc[12] = fmaf(a, w3v.x, acc[12]); acc[13] = fmaf(a, w3v.y, acc[13]);
        acc[14] = fmaf(a, w3v.z, acc[14]); acc[15] = fmaf(a, w3v.w, acc[15]);
      }
#pragma unroll
      for (int x = 0; x < 16; ++x) s_hid[(g * 16 + j) * 132 + d0 + x] = fmaxf(acc[x], 0.f);
    }
    __syncthreads();
    {
      // sim = hidden2 @ pta_w2 + b2 -> overwrite s_sim
      const int j = u >> 3, h0 = (u & 7) * 4;
      float a0 = p.pta_b2[h0 + 0], a1 = p.pta_b2[h0 + 1], a2 = p.pta_b2[h0 + 2], a3 = p.pta_b2[h0 + 3];
      for (int d = 0; d < 128; ++d) {
        const float a = s_hid[(g * 16 + j) * 132 + d];
        const float4 w2 = *(const float4*)&s_wC[d * 32 + h0];
        a0 = fmaf(a, w2.x, a0); a1 = fmaf(a, w2.y, a1);
        a2 = fmaf(a, w2.z, a2); a3 = fmaf(a, w2.w, a3);
      }
      const int base = g * 16 + j;
      s_sim[base * 33 + h0 + 0] = a0; s_sim[base * 33 + h0 + 1] = a1;
      s_sim[base * 33 + h0 + 2] = a2; s_sim[base * 33 + h0 + 3] = a3;
    }
    __syncthreads();
    if (t < 64) {
      // softmax over j and weighted sum with (v + rpe) -> new feats[i]
      const int g2 = t >> 5, h = t & 31, i2 = ig + g2;
      float mx = -1e30f;
#pragma unroll
      for (int j = 0; j < 16; ++j) mx = fmaxf(mx, s_sim[(g2 * 16 + j) * 33 + h]);
      float sum = 0.f, o = 0.f;
#pragma unroll
      for (int j = 0; j < 16; ++j) {
        const float e = __expf(s_sim[(g2 * 16 + j) * 33 + h] - mx);
        sum += e;
        o = fmaf(e, s_v[j * 32 + h] + s_rpe[(g2 * 16 + j) * 32 + h], o);
      }
      s_feats[i2 * 32 + h] = o / sum;
    }
    __syncthreads();
  }

  // ---- restage weights for cross-attention ----
  {
    const float4* srcA = (const float4*)p.cap_w2;
    const float4* srcC = (const float4*)p.caa_w2;
    float4* dA = (float4*)s_wA;
    float4* dC = (float4*)s_wC;
#pragma unroll
    for (int m = 0; m < 4; ++m) {
      dA[t + 256 * m] = srcA[t + 256 * m];
      dC[t + 256 * m] = srcC[t + 256 * m];
    }
  }
  __syncthreads();

  // ---- Phase D: 8 march steps + final epilogue (s==8) ----
  for (int s = 0; s <= 8; ++s) {
    if (s < 8) {
      if (t < 16) {
        const float r0 = s_coords[t * 3 + 0] - s_op[0];
        const float r1 = s_coords[t * 3 + 1] - s_op[1];
        const float r2 = s_coords[t * 3 + 2] - s_op[2];
        const float rd = sqrtf(r0 * r0 + r1 * r1 + r2 * r2);
        s_reld[t] = rd;
        const float inv = 1.f / rd;
        s_relv[t * 3 + 0] = r0 * inv; s_relv[t * 3 + 1] = r1 * inv; s_relv[t * 3 + 2] = r2 * inv;
        p.o_ld[b * 128 + s * 16 + t] = rd;
      } else if (t >= 16 && t < 19) {
        s_opc[t - 16] = s_qry[t - 16] * s_cum;
      }
    } else {
      if (t < 3) s_opc[t] = s_op[t];  // final pass: feat_mlp(op); rel from step 7 kept
    }
    __syncthreads();
    {
      // pe = mlp2(rel_coords) with fused 3->128 hidden
      const int k = t >> 4, h0 = (t & 15) * 2;
      const float rd = s_reld[k];
      const float r0 = s_relv[k * 3 + 0] * rd, r1 = s_relv[k * 3 + 1] * rd, r2 = s_relv[k * 3 + 2] * rd;
      float a0 = p.cap_b2[h0], a1 = p.cap_b2[h0 + 1];
      for (int d = 0; d < 128; ++d) {
        const float hv = fmaxf(fmaf(r0, p.cap_w1[d],
                         fmaf(r1, p.cap_w1[128 + d],
                         fmaf(r2, p.cap_w1[256 + d], p.cap_b1[d]))), 0.f);
        const float2 w2 = *(const float2*)&s_wA[d * 32 + h0];
        a0 = fmaf(hv, w2.x, a0); a1 = fmaf(hv, w2.y, a1);
      }
      s_rpe[k * 32 + h0] = a0; s_rpe[k * 32 + h0 + 1] = a1;
    }
    __syncthreads();
    // feat_mlp(op_coords) -> opf, then qq
    if (t < 32) {
      float a = p.fb1[t];
#pragma unroll
      for (int c = 0; c < 3; ++c) a = fmaf(s_opc[c], p.fw1[c * 32 + t], a);
      s_h1[t] = fmaxf(a, 0.f);
    }
    __syncthreads();
    if (t < 32) {
      float a = p.fb2[t];
      for (int i = 0; i < 32; ++i) a = fmaf(s_h1[i], p.fw2[i * 32 + t], a);
      s_h2[t] = fmaxf(a, 0.f);
    }
    __syncthreads();
    if (t < 32) {
      float a = p.fb3[t];
      for (int i = 0; i < 32; ++i) a = fmaf(s_h2[i], p.fw3[i * 32 + t], a);
      s_opf[t] = a;
    }
    __syncthreads();
    if (t < 32) {
      float a = p.caq_b[t];
      for (int i = 0; i < 32; ++i) a = fmaf(s_opf[i], p.caq_w[i * 32 + t], a);
      s_qq[t] = a;
    }
    __syncthreads();
    // kk, vv(+pe), ain = qq - kk + pe
#pragma unroll
    for (int m = 0; m < 2; ++m) {
      const int l = t + 256 * m, k = l >> 5, h = l & 31;
      float kk = p.cak_b[h], vv = p.cav_b[h];
      for (int i = 0; i < 32; ++i) {
        const float f = s_feats[k * 32 + i];
        kk = fmaf(f, p.cak_w[i * 32 + h], kk);
        vv = fmaf(f, p.cav_w[i * 32 + h], vv);
      }
      const float pe = s_rpe[k * 32 + h];
      s_vv[k * 32 + h] = vv + pe;
      s_sim[k * 33 + h] = s_qq[h] - kk + pe;
    }
    __syncthreads();
    {
      // attn hidden = relu(ain @ caa_w1 + b1)
      const int k = t >> 4, d0 = (t & 15) * 8;
      float acc[8];
#pragma unroll
      for (int x = 0; x < 8; ++x) acc[x] = p.caa_b1[d0 + x];
      for (int h = 0; h < 32; ++h) {
        const float a = s_sim[k * 33 + h];
        const float4 w0 = *(const float4*)&p.caa_w1[h * 128 + d0];
        const float4 w1v = *(const float4*)&p.caa_w1[h * 128 + d0 + 4];
        acc[0] = fmaf(a, w0.x, acc[0]);  acc[1] = fmaf(a, w0.y, acc[1]);
        acc[2] = fmaf(a, w0.z, acc[2]);  acc[3] = fmaf(a, w0.w, acc[3]);
        acc[4] = fmaf(a, w1v.x, acc[4]); acc[5] = fmaf(a, w1v.y, acc[5]);
        acc[6] = fmaf(a, w1v.z, acc[6]); acc[7] = fmaf(a, w1v.w, acc[7]);
      }
#pragma unroll
      for (int x = 0; x < 8; ++x) s_hid[k * 132 + d0 + x] = fmaxf(acc[x], 0.f);
    }
    __syncthreads();
    {
      // attn sim = hidden @ caa_w2 + b2
      const int k = t >> 4, h0 = (t & 15) * 2;
      float a0 = p.caa_b2[h0], a1 = p.caa_b2[h0 + 1];
      for (int d = 0; d < 128; ++d) {
        const float a = s_hid[k * 132 + d];
        const float2 w2 = *(const float2*)&s_wC[d * 32 + h0];
        a0 = fmaf(a, w2.x, a0); a1 = fmaf(a, w2.y, a1);
      }
      s_sim[k * 33 + h0] = a0; s_sim[k * 33 + h0 + 1] = a1;
    }
    __syncthreads();
    // softmax over k + ca
    if (t < 32) {
      const int h = t;
      float mx = -1e30f;
#pragma unroll
      for (int k = 0; k < 16; ++k) mx = fmaxf(mx, s_sim[k * 33 + h]);
      float sum = 0.f, o = 0.f;
#pragma unroll
      for (int k = 0; k < 16; ++k) {
        const float e = __expf(s_sim[k * 33 + h] - mx);
        sum += e;
        o = fmaf(e, s_vv[k * 32 + h], o);
      }
      s_ca[h] = o / sum;
    } else if (t < 35) {
      s_ca[t] = s_qry[t - 32];
    }
    __syncthreads();
    if (s < 8) {
      if (t < 32) {
        float a = p.im_b1[t];
        for (int i = 0; i < 32; ++i) a = fmaf(s_ca[i], p.im_w1[i * 32 + t], a);
        s_h1[t] = fmaxf(a, 0.f);
      }
      __syncthreads();
      if (t < 32) {
        float a = p.im_b2[t];
        for (int i = 0; i < 32; ++i) a = fmaf(s_h1[i], p.im_w2[i * 32 + t], a);
        s_h2[t] = fmaxf(a, 0.f);
      }
      __syncthreads();
      if (t < 3) {
        float a = p.im_b3[t];
        for (int i = 0; i < 32; ++i) a = fmaf(s_h2[i], p.im_w3[i * 3 + t], a);
        s_imp[t] = a;
      }
      __syncthreads();
      if (t == 0) s_step = sqrtf(s_imp[0] * s_imp[0] + s_imp[1] * s_imp[1] + s_imp[2] * s_imp[2]);
      __syncthreads();
      if (t < 3) {
        p.o_ip[(b * 8 + s) * 3 + t] = s_opc[t] + s_imp[t];
        s_tang[t] = s_imp[t] / s_step;
        s_op[t] = s_opc[t] + s_qry[t] * s_step;
      } else if (t == 3) {
        p.o_ms[b * 8 + s] = s_step;
      } else if (t == 4) {
        s_cum += s_step;
      }
      __syncthreads();
      if (t < 16) {
        const float cs = s_tang[0] * s_relv[t * 3 + 0] + s_tang[1] * s_relv[t * 3 + 1]
                       + s_tang[2] * s_relv[t * 3 + 2];
        p.o_cs[b * 128 + s * 16 + t] = cs;
      }
      __syncthreads();
    } else {
      if (t < 32) {
        float a = p.ep_b1[t];
        for (int i = 0; i < 35; ++i) a = fmaf(s_ca[i], p.ep_w1[i * 32 + t], a);
        s_h1[t] = fmaxf(a, 0.f);
      }
      __syncthreads();
      if (t < 32) {
        float a = p.ep_b2[t];
        for (int i = 0; i < 32; ++i) a = fmaf(s_h1[i], p.ep_w2[i * 32 + t], a);
        s_h2[t] = fmaxf(a, 0.f);
      }
      __syncthreads();
      if (t == 0) {
        float a = p.ep_b3[0];
        for (int i = 0; i < 32; ++i) a = fmaf(s_h2[i], p.ep_w3[i], a);
        p.o_eps[b] = a;
        p.o_cum[b] = s_cum;
      }
      __syncthreads();
    }
  }
}

extern "C" void kernel_launch(void* const* d_in, const int* in_sizes, int n_in,
                              void* d_out, int out_size, void* d_ws, size_t ws_size,
                              hipStream_t stream) {
  Params p;
  const float** f = (const float**)(void*)&p;
  for (int i = 0; i < 43; ++i) f[i] = (const float*)d_in[i];
  float* out = (float*)d_out;
  p.o_ld  = out;
  p.o_ms  = out + OFF_MS;
  p.o_cs  = out + OFF_CS;
  p.o_ip  = out + OFF_IP;
  p.o_cum = out + OFF_CUM;
  p.o_eps = out + OFF_EPS;
  puray_kernel<<<dim3(4096), dim3(256), 0, stream>>>(p);
}